// Round 4
// baseline (1049.457 us; speedup 1.0000x reference)
//
#include <hip/hip_runtime.h>
#include <stdint.h>

#define T_TOK 8192
#define DM    2048
#define DFF   2048

typedef __attribute__((ext_vector_type(8))) short bf16x8;
typedef __attribute__((ext_vector_type(4))) float f32x4;
typedef __attribute__((ext_vector_type(4))) int   i32x4;
typedef __attribute__((ext_vector_type(8))) int   i32x8;

// ---- workspace layout (bytes) ----
#define OFF_AMAX  0                         // uint
#define OFF_CNT   64                        // int[16]  (slot*8+expert)
#define OFF_PBASE 128                       // int[16]  padded row base
#define OFF_TMETA 192                       // int[2]: {tiles_slot0, tiles_total}
#define OFF_TSE   256                       // int[160] tile -> bucket
#define OFF_TM0   960                       // int[160] tile -> m0
#define OFF_BTOK  4096                      // int[16][8192]
#define OFF_BW    (OFF_BTOK + 16*T_TOK*4)   // float[16][8192]
#define OFF_XQ    (2*1024*1024)             // fp8[8192][2048]          16 MB
#define OFF_W13F  (OFF_XQ + T_TOK*DM)       // fp8[8][4096][2048]       64 MB
#define OFF_W2B   (OFF_W13F + 8*2*DFF*DM)   // bf16[8][2048][2048]      64 MB
#define OFF_H     (OFF_W2B + 8*DM*DFF*2)    // bf16[18432][2048]        75.5 MB

#define GP(p) ((const __attribute__((address_space(1))) void*)(uintptr_t)(p))
#define LP(p) ((__attribute__((address_space(3))) void*)(uint32_t)(uintptr_t)(p))

__device__ __forceinline__ short bf16_rne(float f) {
    uint32_t b = __float_as_uint(f);
    b += 0x7FFFu + ((b >> 16) & 1u);
    return (short)(b >> 16);
}

// round-to-nearest-even onto the fp8 e4m3fn grid (saturating), returns f32 value
__device__ __forceinline__ float fp8_round(float y) {
    float a = fabsf(y);
    a = fminf(a, 448.f);
    uint32_t b = __float_as_uint(a);
    if (b >= 0x3C800000u) {                 // >= 2^-6 : normal range, keep 3 mantissa bits
        uint32_t lsb = (b >> 20) & 1u;
        b += 0x7FFFFu + lsb;
        b &= 0xFFF00000u;
        a = __uint_as_float(b);
    } else {                                // subnormal: quantum 2^-9
        a = rintf(a * 512.f) * (1.f / 512.f);
    }
    return (y < 0.f) ? -a : a;
}

// exact e4m3fn encode for values ALREADY on the fp8 grid (|v| <= 448)
__device__ __forceinline__ unsigned char fp8_enc(float v) {
    uint32_t b = __float_as_uint(v);
    uint32_t s = (b >> 24) & 0x80u;
    float a = fabsf(v);
    uint32_t q;
    if (a < 0.015625f) {                    // subnormal: k * 2^-9, k in 0..7
        q = (uint32_t)(a * 512.0f + 0.5f);
    } else {
        uint32_t e = (b >> 23) & 0xFFu;     // 121..135
        uint32_t m = (b >> 20) & 7u;        // top-3 mantissa (rest zero: on-grid)
        q = ((e - 120u) << 3) | m;
    }
    return (unsigned char)(s | q);
}

// ---------------- small kernels ----------------
__global__ void k_amax(const float4* __restrict__ x, unsigned* __restrict__ amax) {
    __shared__ float red[256];
    float m = 0.f;
    const int n4 = T_TOK * DM / 4;
    for (int i = blockIdx.x * blockDim.x + threadIdx.x; i < n4; i += gridDim.x * blockDim.x) {
        float4 v = x[i];
        m = fmaxf(m, fmaxf(fmaxf(fabsf(v.x), fabsf(v.y)), fmaxf(fabsf(v.z), fabsf(v.w))));
    }
    red[threadIdx.x] = m;
    __syncthreads();
    for (int s = 128; s > 0; s >>= 1) {
        if (threadIdx.x < s) red[threadIdx.x] = fmaxf(red[threadIdx.x], red[threadIdx.x + s]);
        __syncthreads();
    }
    if (threadIdx.x == 0) atomicMax(amax, __float_as_uint(red[0]));
}

__global__ void k_router(const float* __restrict__ gating, int* __restrict__ cnt,
                         int* __restrict__ btok, float* __restrict__ bw) {
    __shared__ int lcnt[16];
    __shared__ int lbase[16];
    const int tid = threadIdx.x;
    if (tid < 16) lcnt[tid] = 0;
    __syncthreads();
    const int t = blockIdx.x * 256 + tid;
    float l[8], p[8];
    float lmax = -1e30f;
#pragma unroll
    for (int i = 0; i < 8; i++) { l[i] = gating[t * 8 + i]; lmax = fmaxf(lmax, l[i]); }
    float s = 0.f;
#pragma unroll
    for (int i = 0; i < 8; i++) { p[i] = __expf(l[i] - lmax); s += p[i]; }
    int i0 = 0;
#pragma unroll
    for (int i = 1; i < 8; i++) if (l[i] > l[i0]) i0 = i;
    int i1 = (i0 == 0) ? 1 : 0;
#pragma unroll
    for (int i = 0; i < 8; i++) if (i != i1 && i != i0 && l[i] > l[i1]) i1 = i;
    float pa = p[i0] / s, pb = p[i1] / s;
    float w0 = pa / (pa + pb), w1 = pb / (pa + pb);
    int p0 = atomicAdd(&lcnt[i0], 1);
    int p1 = atomicAdd(&lcnt[8 + i1], 1);
    __syncthreads();
    if (tid < 16) lbase[tid] = atomicAdd(&cnt[tid], lcnt[tid]);
    __syncthreads();
    int pos = lbase[i0] + p0;
    btok[i0 * T_TOK + pos] = t; bw[i0 * T_TOK + pos] = w0;
    pos = lbase[8 + i1] + p1;
    btok[(8 + i1) * T_TOK + pos] = t; bw[(8 + i1) * T_TOK + pos] = w1;
}

// parallel tile-table builder
__global__ void k_build(const int* __restrict__ cnt, int* __restrict__ pbase,
                        int* __restrict__ tmeta, int* __restrict__ tse, int* __restrict__ tm0) {
    __shared__ int nt[16], rbase[16], tstart[17];
    const int tid = threadIdx.x;
    if (tid < 16) nt[tid] = (cnt[tid] + 127) >> 7;
    __syncthreads();
    if (tid == 0) {
        int b = 0, t = 0;
        for (int i = 0; i < 16; i++) {
            rbase[i] = b; tstart[i] = t;
            b += nt[i] << 7; t += nt[i];
        }
        tstart[16] = t;
        tmeta[0] = tstart[8]; tmeta[1] = t;
    }
    __syncthreads();
    if (tid < 16) pbase[tid] = rbase[tid];
    const int tt = tstart[16];
    if (tid < tt) {
        int b = 0;
        while (tstart[b + 1] <= tid) b++;
        tse[tid] = b;
        tm0[tid] = (tid - tstart[b]) << 7;
    }
}

__global__ void k_quant(const float4* __restrict__ x, unsigned char* __restrict__ xq,
                        const unsigned* __restrict__ amax) {
    float scale = fmaxf(__uint_as_float(*amax), 1e-12f) / 448.f;
    const int n4 = T_TOK * DM / 4;
    for (int i = blockIdx.x * blockDim.x + threadIdx.x; i < n4; i += gridDim.x * blockDim.x) {
        float4 v = x[i];
        uchar4 o;
        o.x = fp8_enc(fp8_round(v.x / scale));
        o.y = fp8_enc(fp8_round(v.y / scale));
        o.z = fp8_enc(fp8_round(v.z / scale));
        o.w = fp8_enc(fp8_round(v.w / scale));
        ((uchar4*)xq)[i] = o;
    }
}

// fused weight conversion: w13 f32->fp8 bytes, w2 f32->bf16 (one dispatch)
#define N13_4 (8 * 2 * DFF * DM / 4)
#define N2_4  (8 * DM * DFF / 4)
__global__ void k_convw(const float4* __restrict__ w13, unsigned char* __restrict__ o13,
                        const float4* __restrict__ w2, short* __restrict__ o2) {
    for (int i = blockIdx.x * blockDim.x + threadIdx.x; i < N13_4 + N2_4; i += gridDim.x * blockDim.x) {
        if (i < N13_4) {
            float4 v = w13[i];
            uchar4 q;
            q.x = fp8_enc(v.x); q.y = fp8_enc(v.y); q.z = fp8_enc(v.z); q.w = fp8_enc(v.w);
            ((uchar4*)o13)[i] = q;
        } else {
            int j = i - N13_4;
            float4 v = w2[j];
            short4 q;
            q.x = bf16_rne(v.x); q.y = bf16_rne(v.y); q.z = bf16_rne(v.z); q.w = bf16_rne(v.w);
            ((short4*)o2)[j] = q;
        }
    }
}

// ---- GEMM1 (MX-fp8 K=128): h = silu(xq@Wg^T * s1) * (xq@Wu^T * s1) * combine ----
// k-permuted LDS storage: physical chunk p of row r holds global chunk perm(p ^ (r&7)),
// perm(s) = s<4 ? 2s : 2s-7. Fragment fk reads physical chunks fk^(r&7), (fk^(r&7))^4.
__launch_bounds__(256, 4)
__global__ void k_gemm1(const unsigned char* __restrict__ xq, const unsigned char* __restrict__ w13f,
                        short* __restrict__ hbuf, const char* __restrict__ ws,
                        const float* __restrict__ w13_scale) {
    const int* cnt   = (const int*)(ws + OFF_CNT);
    const int* pbase = (const int*)(ws + OFF_PBASE);
    const int* tmeta = (const int*)(ws + OFF_TMETA);
    const int* tse   = (const int*)(ws + OFF_TSE);
    const int* tm0a  = (const int*)(ws + OFF_TM0);
    const int* btok  = (const int*)(ws + OFF_BTOK);
    const float* bwt = (const float*)(ws + OFF_BW);

    int ti = blockIdx.y;
    if (ti >= tmeta[1]) return;
    const int b = tse[ti], m0 = tm0a[ti], e = b & 7, c_n = cnt[b];
    const int hbase = pbase[b] + m0;
    const int n0 = blockIdx.x * 64;

    const int tid = threadIdx.x, w = tid >> 6, l = tid & 63;
    __shared__ i32x4 smv[2048];             // 32 KB: A fp8 [0,16K), B fp8 [16K,32K)
    char* sm = (char*)smv;

    const int rb = w * 8 + (l >> 3);
    const int s8 = (l & 7) ^ (l >> 3);
    const int gchunk = (s8 < 4) ? (s8 << 1) : ((s8 << 1) - 7);   // perm
    const int* btk = btok + b * T_TOK;
    const unsigned char* ap[4];
    const unsigned char* bp[4];
#pragma unroll
    for (int c = 0; c < 4; c++) {
        int r = c * 32 + rb;
        int rr = m0 + r; if (rr >= c_n) rr = c_n - 1;
        ap[c] = xq + (size_t)btk[rr] * DM + gchunk * 16;
        int wr = (r < 64) ? (n0 + r) : (DFF + n0 + (r - 64));
        bp[c] = w13f + (size_t)e * (2 * DFF) * DM + (size_t)wr * DM + gchunk * 16;
    }

    f32x4 zero = {0.f, 0.f, 0.f, 0.f};
    f32x4 acc[4][4];
#pragma unroll
    for (int i = 0; i < 4; i++)
#pragma unroll
        for (int j = 0; j < 4; j++) acc[i][j] = zero;

    const int mw = w & 1, nw = w >> 1;
    const int fr = l & 15, fk = l >> 4;

    for (int kt = 0; kt < 16; kt++) {
        const int ko = kt * 128;
#pragma unroll
        for (int c = 0; c < 4; c++)
            __builtin_amdgcn_global_load_lds(GP(ap[c] + ko), LP(sm + c * 4096 + w * 1024), 16, 0, 0);
#pragma unroll
        for (int c = 0; c < 4; c++)
            __builtin_amdgcn_global_load_lds(GP(bp[c] + ko), LP(sm + 16384 + c * 4096 + w * 1024), 16, 0, 0);
        asm volatile("s_waitcnt vmcnt(0)" ::: "memory");
        __syncthreads();

        i32x8 af[4], bf[4];
#pragma unroll
        for (int i = 0; i < 4; i++) {
            int row = mw * 64 + i * 16 + fr;
            const char* base = sm + row * 128;
            int pc = fk ^ (row & 7);
            i32x4 lo = *(const i32x4*)(base + (pc << 4));
            i32x4 hi = *(const i32x4*)(base + ((pc ^ 4) << 4));
            af[i][0] = lo[0]; af[i][1] = lo[1]; af[i][2] = lo[2]; af[i][3] = lo[3];
            af[i][4] = hi[0]; af[i][5] = hi[1]; af[i][6] = hi[2]; af[i][7] = hi[3];
        }
#pragma unroll
        for (int j = 0; j < 4; j++) {
            int row = nw * 64 + j * 16 + fr;
            const char* base = sm + 16384 + row * 128;
            int pc = fk ^ (row & 7);
            i32x4 lo = *(const i32x4*)(base + (pc << 4));
            i32x4 hi = *(const i32x4*)(base + ((pc ^ 4) << 4));
            bf[j][0] = lo[0]; bf[j][1] = lo[1]; bf[j][2] = lo[2]; bf[j][3] = lo[3];
            bf[j][4] = hi[0]; bf[j][5] = hi[1]; bf[j][6] = hi[2]; bf[j][7] = hi[3];
        }
#pragma unroll
        for (int i = 0; i < 4; i++)
#pragma unroll
            for (int j = 0; j < 4; j++)
                acc[i][j] = __builtin_amdgcn_mfma_scale_f32_16x16x128_f8f6f4(
                    af[i], bf[j], acc[i][j], 0, 0, 0, 0x7F7F7F7F, 0, 0x7F7F7F7F);
        __syncthreads();
    }

    // epilogue: nw==1 waves hold "up", nw==0 hold "gate" for the same local cols
    const float sx = fmaxf(__uint_as_float(*(const unsigned*)(ws + OFF_AMAX)), 1e-12f) / 448.f;
    const float s1 = sx * w13_scale[e];
    float* U = (float*)sm;                  // 2 * 64 * 64 f32 = 32 KB, exact fit
    if (nw == 1) {
#pragma unroll
        for (int i = 0; i < 4; i++)
#pragma unroll
            for (int j = 0; j < 4; j++)
#pragma unroll
                for (int r = 0; r < 4; r++) {
                    int lm = i * 16 + fk * 4 + r, col = j * 16 + fr;
                    U[mw * 4096 + lm * 64 + col] = acc[i][j][r];
                }
    }
    __syncthreads();
    if (nw == 0) {
#pragma unroll
        for (int i = 0; i < 4; i++)
#pragma unroll
            for (int j = 0; j < 4; j++)
#pragma unroll
                for (int r = 0; r < 4; r++) {
                    int lml = i * 16 + fk * 4 + r;
                    int lm = mw * 64 + lml, col = j * 16 + fr;
                    float g = acc[i][j][r] * s1;
                    float u = U[mw * 4096 + lml * 64 + col] * s1;
                    float cc = (m0 + lm < c_n) ? bwt[b * T_TOK + m0 + lm] : 0.f;
                    float h = g / (1.f + __expf(-g)) * u * cc;
                    hbuf[(size_t)(hbase + lm) * DFF + n0 + col] = bf16_rne(h);
                }
    }
}

// ---- GEMM2 (bf16, single atomic pass): out += (h @ w2^T) * w2_scale ----
__launch_bounds__(256, 4)
__global__ void k_gemm2(const short* __restrict__ hbuf, const short* __restrict__ w2b,
                        float* __restrict__ out, const char* __restrict__ ws,
                        const float* __restrict__ w2_scale) {
    const int* cnt   = (const int*)(ws + OFF_CNT);
    const int* pbase = (const int*)(ws + OFF_PBASE);
    const int* tmeta = (const int*)(ws + OFF_TMETA);
    const int* tse   = (const int*)(ws + OFF_TSE);
    const int* tm0a  = (const int*)(ws + OFF_TM0);
    const int* btok  = (const int*)(ws + OFF_BTOK);

    int ti = blockIdx.y;
    if (ti >= tmeta[1]) return;
    const int b = tse[ti], m0 = tm0a[ti], e = b & 7, c_n = cnt[b];
    const int hb = pbase[b] + m0;
    const int n0 = blockIdx.x * 128;

    const int tid = threadIdx.x, w = tid >> 6, l = tid & 63;
    __shared__ i32x4 smv2[2048];
    short* sm = (short*)smv2;

    const int rb = w * 8 + (l >> 3);
    const int gchunk = (l & 7) ^ (l >> 3);
    const short* ap[4];
    const short* bp[4];
#pragma unroll
    for (int c = 0; c < 4; c++) {
        int r = c * 32 + rb;
        ap[c] = hbuf + (size_t)(hb + r) * DFF + gchunk * 8;
        bp[c] = w2b + (size_t)e * DM * DFF + (size_t)(n0 + r) * DFF + gchunk * 8;
    }

    f32x4 zero = {0.f, 0.f, 0.f, 0.f};
    f32x4 acc[4][4];
#pragma unroll
    for (int i = 0; i < 4; i++)
#pragma unroll
        for (int j = 0; j < 4; j++) acc[i][j] = zero;

    const int mw = w & 1, nw = w >> 1;
    const int fr = l & 15, fk = l >> 4;

    for (int kt = 0; kt < 32; kt++) {
        const int ko = kt * 64;
#pragma unroll
        for (int c = 0; c < 4; c++)
            __builtin_amdgcn_global_load_lds(GP(ap[c] + ko), LP(sm + c * 2048 + w * 512), 16, 0, 0);
#pragma unroll
        for (int c = 0; c < 4; c++)
            __builtin_amdgcn_global_load_lds(GP(bp[c] + ko), LP(sm + 8192 + c * 2048 + w * 512), 16, 0, 0);
        asm volatile("s_waitcnt vmcnt(0)" ::: "memory");
        __syncthreads();
#pragma unroll
        for (int kk = 0; kk < 2; kk++) {
            const int g = kk * 4 + fk;
            bf16x8 af[4], bfr[4];
#pragma unroll
            for (int i = 0; i < 4; i++) {
                int row = mw * 64 + i * 16 + fr;
                af[i] = *(const bf16x8*)&sm[row * 64 + ((g ^ (row & 7)) << 3)];
            }
#pragma unroll
            for (int j = 0; j < 4; j++) {
                int row = nw * 64 + j * 16 + fr;
                bfr[j] = *(const bf16x8*)&sm[8192 + row * 64 + ((g ^ (row & 7)) << 3)];
            }
#pragma unroll
            for (int i = 0; i < 4; i++)
#pragma unroll
                for (int j = 0; j < 4; j++)
                    acc[i][j] = __builtin_amdgcn_mfma_f32_16x16x32_bf16(af[i], bfr[j], acc[i][j], 0, 0, 0);
        }
        __syncthreads();
    }

    const float s2 = w2_scale[e];
#pragma unroll
    for (int i = 0; i < 4; i++)
#pragma unroll
        for (int r = 0; r < 4; r++) {
            int lm = mw * 64 + i * 16 + fk * 4 + r;
            if (m0 + lm < c_n) {
                int tok = btok[b * T_TOK + m0 + lm];
#pragma unroll
                for (int j = 0; j < 4; j++) {
                    int col = n0 + nw * 64 + j * 16 + fr;
                    atomicAdd(out + (size_t)tok * DM + col, acc[i][j][r] * s2);
                }
            }
        }
}

extern "C" void kernel_launch(void* const* d_in, const int* in_sizes, int n_in,
                              void* d_out, int out_size, void* d_ws, size_t ws_size,
                              hipStream_t stream) {
    const float* x      = (const float*)d_in[0];
    const float* gating = (const float*)d_in[1];
    const float* w13q   = (const float*)d_in[2];
    const float* w13s   = (const float*)d_in[3];
    const float* w2q    = (const float*)d_in[4];
    const float* w2s    = (const float*)d_in[5];
    float* out = (float*)d_out;
    char* ws = (char*)d_ws;

    hipMemsetAsync(ws, 0, 4096, stream);
    hipMemsetAsync(out, 0, (size_t)T_TOK * DM * sizeof(float), stream);
    k_amax<<<1024, 256, 0, stream>>>((const float4*)x, (unsigned*)(ws + OFF_AMAX));
    k_router<<<T_TOK / 256, 256, 0, stream>>>(gating, (int*)(ws + OFF_CNT),
                                              (int*)(ws + OFF_BTOK), (float*)(ws + OFF_BW));
    k_build<<<1, 256, 0, stream>>>((const int*)(ws + OFF_CNT), (int*)(ws + OFF_PBASE),
                                   (int*)(ws + OFF_TMETA), (int*)(ws + OFF_TSE), (int*)(ws + OFF_TM0));
    k_quant<<<1024, 256, 0, stream>>>((const float4*)x, (unsigned char*)(ws + OFF_XQ),
                                      (const unsigned*)(ws + OFF_AMAX));
    k_convw<<<3072, 256, 0, stream>>>((const float4*)w13q, (unsigned char*)(ws + OFF_W13F),
                                      (const float4*)w2q, (short*)(ws + OFF_W2B));
    k_gemm1<<<dim3(32, 144), 256, 0, stream>>>((const unsigned char*)(ws + OFF_XQ),
                                               (const unsigned char*)(ws + OFF_W13F),
                                               (short*)(ws + OFF_H), ws, w13s);
    k_gemm2<<<dim3(16, 144), 256, 0, stream>>>((const short*)(ws + OFF_H), (const short*)(ws + OFF_W2B),
                                               out, ws, w2s);
}

// Round 5
// 946.688 us; speedup vs baseline: 1.1086x; 1.1086x over previous
//
#include <hip/hip_runtime.h>
#include <stdint.h>

#define T_TOK 8192
#define DM    2048
#define DFF   2048

typedef __attribute__((ext_vector_type(8))) short bf16x8;
typedef __attribute__((ext_vector_type(4))) float f32x4;
typedef __attribute__((ext_vector_type(4))) int   i32x4;
typedef __attribute__((ext_vector_type(8))) int   i32x8;

// ---- workspace layout (bytes) ----
#define OFF_AMAX  0                         // uint
#define OFF_CNT   64                        // int[16]  (slot*8+expert)
#define OFF_PBASE 128                       // int[16]  padded row base
#define OFF_TMETA 192                       // int[2]: {tiles_slot0, tiles_total}
#define OFF_TSE   256                       // int[160] tile -> bucket
#define OFF_TM0   960                       // int[160] tile -> m0
#define OFF_BTOK  4096                      // int[16][8192]
#define OFF_BW    (OFF_BTOK + 16*T_TOK*4)   // float[16][8192]
#define OFF_XQ    (2*1024*1024)             // fp8[8192][2048]          16 MB
#define OFF_W13F  (OFF_XQ + T_TOK*DM)       // fp8[8][4096][2048]       64 MB
#define OFF_W2B   (OFF_W13F + 8*2*DFF*DM)   // bf16[8][2048][2048]      64 MB
#define OFF_H     (OFF_W2B + 8*DM*DFF*2)    // bf16[18432][2048]        75.5 MB

#define GP(p) ((const __attribute__((address_space(1))) void*)(uintptr_t)(p))
#define LP(p) ((__attribute__((address_space(3))) void*)(uint32_t)(uintptr_t)(p))

__device__ __forceinline__ short bf16_rne(float f) {
    uint32_t b = __float_as_uint(f);
    b += 0x7FFFu + ((b >> 16) & 1u);
    return (short)(b >> 16);
}

// round-to-nearest-even onto the fp8 e4m3fn grid (saturating), returns f32 value
__device__ __forceinline__ float fp8_round(float y) {
    float a = fabsf(y);
    a = fminf(a, 448.f);
    uint32_t b = __float_as_uint(a);
    if (b >= 0x3C800000u) {                 // >= 2^-6 : normal range, keep 3 mantissa bits
        uint32_t lsb = (b >> 20) & 1u;
        b += 0x7FFFFu + lsb;
        b &= 0xFFF00000u;
        a = __uint_as_float(b);
    } else {                                // subnormal: quantum 2^-9
        a = rintf(a * 512.f) * (1.f / 512.f);
    }
    return (y < 0.f) ? -a : a;
}

// exact e4m3fn encode for values ALREADY on the fp8 grid (|v| <= 448)
__device__ __forceinline__ unsigned char fp8_enc(float v) {
    uint32_t b = __float_as_uint(v);
    uint32_t s = (b >> 24) & 0x80u;
    float a = fabsf(v);
    uint32_t q;
    if (a < 0.015625f) {                    // subnormal: k * 2^-9, k in 0..7
        q = (uint32_t)(a * 512.0f + 0.5f);
    } else {
        uint32_t e = (b >> 23) & 0xFFu;     // 121..135
        uint32_t m = (b >> 20) & 7u;        // top-3 mantissa (rest zero: on-grid)
        q = ((e - 120u) << 3) | m;
    }
    return (unsigned char)(s | q);
}

// ---- fused front kernel: blocks 0..31 router, blocks 32..1055 amax(x) + zero(out) ----
__global__ void k_front(const float* __restrict__ gating, int* __restrict__ cnt,
                        int* __restrict__ btok, float* __restrict__ bw,
                        const float4* __restrict__ x, float4* __restrict__ outz,
                        unsigned* __restrict__ amax) {
    const int tid = threadIdx.x;
    if (blockIdx.x < 32) {
        // ---- router ----
        __shared__ int lcnt[16];
        __shared__ int lbase[16];
        if (tid < 16) lcnt[tid] = 0;
        __syncthreads();
        const int t = blockIdx.x * 256 + tid;
        float l[8], p[8];
        float lmax = -1e30f;
#pragma unroll
        for (int i = 0; i < 8; i++) { l[i] = gating[t * 8 + i]; lmax = fmaxf(lmax, l[i]); }
        float s = 0.f;
#pragma unroll
        for (int i = 0; i < 8; i++) { p[i] = __expf(l[i] - lmax); s += p[i]; }
        int i0 = 0;
#pragma unroll
        for (int i = 1; i < 8; i++) if (l[i] > l[i0]) i0 = i;
        int i1 = (i0 == 0) ? 1 : 0;
#pragma unroll
        for (int i = 0; i < 8; i++) if (i != i1 && i != i0 && l[i] > l[i1]) i1 = i;
        float pa = p[i0] / s, pb = p[i1] / s;
        float w0 = pa / (pa + pb), w1 = pb / (pa + pb);
        int p0 = atomicAdd(&lcnt[i0], 1);
        int p1 = atomicAdd(&lcnt[8 + i1], 1);
        __syncthreads();
        if (tid < 16) lbase[tid] = atomicAdd(&cnt[tid], lcnt[tid]);
        __syncthreads();
        int pos = lbase[i0] + p0;
        btok[i0 * T_TOK + pos] = t; bw[i0 * T_TOK + pos] = w0;
        pos = lbase[8 + i1] + p1;
        btok[(8 + i1) * T_TOK + pos] = t; bw[(8 + i1) * T_TOK + pos] = w1;
    } else {
        // ---- amax(x) + zero(out); out and x have the same float4 count ----
        __shared__ float red[256];
        const float4 z = {0.f, 0.f, 0.f, 0.f};
        float m = 0.f;
        const int n4 = T_TOK * DM / 4;
        for (int i = (blockIdx.x - 32) * 256 + tid; i < n4; i += 1024 * 256) {
            float4 v = x[i];
            outz[i] = z;
            m = fmaxf(m, fmaxf(fmaxf(fabsf(v.x), fabsf(v.y)), fmaxf(fabsf(v.z), fabsf(v.w))));
        }
        red[tid] = m;
        __syncthreads();
        for (int s = 128; s > 0; s >>= 1) {
            if (tid < s) red[tid] = fmaxf(red[tid], red[tid + s]);
            __syncthreads();
        }
        if (tid == 0) atomicMax(amax, __float_as_uint(red[0]));
    }
}

// ---- quant (all blocks) + tile-table build (block 0 prologue) ----
__global__ void k_quant(const float4* __restrict__ x, unsigned char* __restrict__ xq,
                        const unsigned* __restrict__ amax, const int* __restrict__ cnt,
                        int* __restrict__ pbase, int* __restrict__ tmeta,
                        int* __restrict__ tse, int* __restrict__ tm0) {
    const int tid = threadIdx.x;
    if (blockIdx.x == 0) {
        __shared__ int nt[16], tstart[17];
        if (tid < 16) nt[tid] = (cnt[tid] + 127) >> 7;
        __syncthreads();
        if (tid == 0) {
            int b = 0, t = 0;
            for (int i = 0; i < 16; i++) {
                pbase[i] = b; tstart[i] = t;
                b += nt[i] << 7; t += nt[i];
            }
            tstart[16] = t;
            tmeta[0] = tstart[8]; tmeta[1] = t;
        }
        __syncthreads();
        const int tt = tstart[16];
        if (tid < tt) {
            int b = 0;
            while (tstart[b + 1] <= tid) b++;
            tse[tid] = b;
            tm0[tid] = (tid - tstart[b]) << 7;
        }
    }
    float scale = fmaxf(__uint_as_float(*amax), 1e-12f) / 448.f;
    const int n4 = T_TOK * DM / 4;
    for (int i = blockIdx.x * blockDim.x + tid; i < n4; i += gridDim.x * blockDim.x) {
        float4 v = x[i];
        uchar4 o;
        o.x = fp8_enc(fp8_round(v.x / scale));
        o.y = fp8_enc(fp8_round(v.y / scale));
        o.z = fp8_enc(fp8_round(v.z / scale));
        o.w = fp8_enc(fp8_round(v.w / scale));
        ((uchar4*)xq)[i] = o;
    }
}

// fused weight conversion: w13 f32->fp8 bytes, w2 f32->bf16 (one dispatch)
#define N13_4 (8 * 2 * DFF * DM / 4)
#define N2_4  (8 * DM * DFF / 4)
__global__ void k_convw(const float4* __restrict__ w13, unsigned char* __restrict__ o13,
                        const float4* __restrict__ w2, short* __restrict__ o2) {
    for (int i = blockIdx.x * blockDim.x + threadIdx.x; i < N13_4 + N2_4; i += gridDim.x * blockDim.x) {
        if (i < N13_4) {
            float4 v = w13[i];
            uchar4 q;
            q.x = fp8_enc(v.x); q.y = fp8_enc(v.y); q.z = fp8_enc(v.z); q.w = fp8_enc(v.w);
            ((uchar4*)o13)[i] = q;
        } else {
            int j = i - N13_4;
            float4 v = w2[j];
            short4 q;
            q.x = bf16_rne(v.x); q.y = bf16_rne(v.y); q.z = bf16_rne(v.z); q.w = bf16_rne(v.w);
            ((short4*)o2)[j] = q;
        }
    }
}

// ---- GEMM1 (MX-fp8 K=128): h = silu(xq@Wg^T * s1) * (xq@Wu^T * s1) * combine ----
// k-permuted LDS storage: physical chunk p of row r holds global chunk perm(p ^ (r&7)),
// perm(s) = s<4 ? 2s : 2s-7. Fragment fk reads physical chunks fk^(r&7), (fk^(r&7))^4.
// NOTE: (256,2) is required -- unified reg use is ~140/wave (76 VGPR + 64 AGPR acc);
// (256,4) forces a 128-reg budget -> AGPR spill to scratch (R4: WRITE_SIZE 430 MB).
__launch_bounds__(256, 2)
__global__ void k_gemm1(const unsigned char* __restrict__ xq, const unsigned char* __restrict__ w13f,
                        short* __restrict__ hbuf, const char* __restrict__ ws,
                        const float* __restrict__ w13_scale) {
    const int* cnt   = (const int*)(ws + OFF_CNT);
    const int* pbase = (const int*)(ws + OFF_PBASE);
    const int* tmeta = (const int*)(ws + OFF_TMETA);
    const int* tse   = (const int*)(ws + OFF_TSE);
    const int* tm0a  = (const int*)(ws + OFF_TM0);
    const int* btok  = (const int*)(ws + OFF_BTOK);
    const float* bwt = (const float*)(ws + OFF_BW);

    int ti = blockIdx.y;
    if (ti >= tmeta[1]) return;
    const int b = tse[ti], m0 = tm0a[ti], e = b & 7, c_n = cnt[b];
    const int hbase = pbase[b] + m0;
    const int n0 = blockIdx.x * 64;

    const int tid = threadIdx.x, w = tid >> 6, l = tid & 63;
    __shared__ i32x4 smv[2048];             // 32 KB: A fp8 [0,16K), B fp8 [16K,32K)
    char* sm = (char*)smv;

    const int rb = w * 8 + (l >> 3);
    const int s8 = (l & 7) ^ (l >> 3);
    const int gchunk = (s8 < 4) ? (s8 << 1) : ((s8 << 1) - 7);   // perm
    const int* btk = btok + b * T_TOK;
    const unsigned char* ap[4];
    const unsigned char* bp[4];
#pragma unroll
    for (int c = 0; c < 4; c++) {
        int r = c * 32 + rb;
        int rr = m0 + r; if (rr >= c_n) rr = c_n - 1;
        ap[c] = xq + (size_t)btk[rr] * DM + gchunk * 16;
        int wr = (r < 64) ? (n0 + r) : (DFF + n0 + (r - 64));
        bp[c] = w13f + (size_t)e * (2 * DFF) * DM + (size_t)wr * DM + gchunk * 16;
    }

    f32x4 zero = {0.f, 0.f, 0.f, 0.f};
    f32x4 acc[4][4];
#pragma unroll
    for (int i = 0; i < 4; i++)
#pragma unroll
        for (int j = 0; j < 4; j++) acc[i][j] = zero;

    const int mw = w & 1, nw = w >> 1;
    const int fr = l & 15, fk = l >> 4;

    for (int kt = 0; kt < 16; kt++) {
        const int ko = kt * 128;
#pragma unroll
        for (int c = 0; c < 4; c++)
            __builtin_amdgcn_global_load_lds(GP(ap[c] + ko), LP(sm + c * 4096 + w * 1024), 16, 0, 0);
#pragma unroll
        for (int c = 0; c < 4; c++)
            __builtin_amdgcn_global_load_lds(GP(bp[c] + ko), LP(sm + 16384 + c * 4096 + w * 1024), 16, 0, 0);
        asm volatile("s_waitcnt vmcnt(0)" ::: "memory");
        __syncthreads();

        i32x8 af[4], bf[4];
#pragma unroll
        for (int i = 0; i < 4; i++) {
            int row = mw * 64 + i * 16 + fr;
            const char* base = sm + row * 128;
            int pc = fk ^ (row & 7);
            i32x4 lo = *(const i32x4*)(base + (pc << 4));
            i32x4 hi = *(const i32x4*)(base + ((pc ^ 4) << 4));
            af[i][0] = lo[0]; af[i][1] = lo[1]; af[i][2] = lo[2]; af[i][3] = lo[3];
            af[i][4] = hi[0]; af[i][5] = hi[1]; af[i][6] = hi[2]; af[i][7] = hi[3];
        }
#pragma unroll
        for (int j = 0; j < 4; j++) {
            int row = nw * 64 + j * 16 + fr;
            const char* base = sm + 16384 + row * 128;
            int pc = fk ^ (row & 7);
            i32x4 lo = *(const i32x4*)(base + (pc << 4));
            i32x4 hi = *(const i32x4*)(base + ((pc ^ 4) << 4));
            bf[j][0] = lo[0]; bf[j][1] = lo[1]; bf[j][2] = lo[2]; bf[j][3] = lo[3];
            bf[j][4] = hi[0]; bf[j][5] = hi[1]; bf[j][6] = hi[2]; bf[j][7] = hi[3];
        }
#pragma unroll
        for (int i = 0; i < 4; i++)
#pragma unroll
            for (int j = 0; j < 4; j++)
                acc[i][j] = __builtin_amdgcn_mfma_scale_f32_16x16x128_f8f6f4(
                    af[i], bf[j], acc[i][j], 0, 0, 0, 0x7F7F7F7F, 0, 0x7F7F7F7F);
        __syncthreads();
    }

    // epilogue: nw==1 waves hold "up", nw==0 hold "gate" for the same local cols
    const float sx = fmaxf(__uint_as_float(*(const unsigned*)(ws + OFF_AMAX)), 1e-12f) / 448.f;
    const float s1 = sx * w13_scale[e];
    float* U = (float*)sm;                  // 2 * 64 * 64 f32 = 32 KB, exact fit
    if (nw == 1) {
#pragma unroll
        for (int i = 0; i < 4; i++)
#pragma unroll
            for (int j = 0; j < 4; j++)
#pragma unroll
                for (int r = 0; r < 4; r++) {
                    int lm = i * 16 + fk * 4 + r, col = j * 16 + fr;
                    U[mw * 4096 + lm * 64 + col] = acc[i][j][r];
                }
    }
    __syncthreads();
    if (nw == 0) {
#pragma unroll
        for (int i = 0; i < 4; i++)
#pragma unroll
            for (int j = 0; j < 4; j++)
#pragma unroll
                for (int r = 0; r < 4; r++) {
                    int lml = i * 16 + fk * 4 + r;
                    int lm = mw * 64 + lml, col = j * 16 + fr;
                    float g = acc[i][j][r] * s1;
                    float u = U[mw * 4096 + lml * 64 + col] * s1;
                    float cc = (m0 + lm < c_n) ? bwt[b * T_TOK + m0 + lm] : 0.f;
                    float h = g / (1.f + __expf(-g)) * u * cc;
                    hbuf[(size_t)(hbase + lm) * DFF + n0 + col] = bf16_rne(h);
                }
    }
}

// ---- GEMM2 (bf16, single atomic pass): out += (h @ w2^T) * w2_scale ----
__launch_bounds__(256, 2)
__global__ void k_gemm2(const short* __restrict__ hbuf, const short* __restrict__ w2b,
                        float* __restrict__ out, const char* __restrict__ ws,
                        const float* __restrict__ w2_scale) {
    const int* cnt   = (const int*)(ws + OFF_CNT);
    const int* pbase = (const int*)(ws + OFF_PBASE);
    const int* tmeta = (const int*)(ws + OFF_TMETA);
    const int* tse   = (const int*)(ws + OFF_TSE);
    const int* tm0a  = (const int*)(ws + OFF_TM0);
    const int* btok  = (const int*)(ws + OFF_BTOK);

    int ti = blockIdx.y;
    if (ti >= tmeta[1]) return;
    const int b = tse[ti], m0 = tm0a[ti], e = b & 7, c_n = cnt[b];
    const int hb = pbase[b] + m0;
    const int n0 = blockIdx.x * 128;

    const int tid = threadIdx.x, w = tid >> 6, l = tid & 63;
    __shared__ i32x4 smv2[2048];
    short* sm = (short*)smv2;

    const int rb = w * 8 + (l >> 3);
    const int gchunk = (l & 7) ^ (l >> 3);
    const short* ap[4];
    const short* bp[4];
#pragma unroll
    for (int c = 0; c < 4; c++) {
        int r = c * 32 + rb;
        ap[c] = hbuf + (size_t)(hb + r) * DFF + gchunk * 8;
        bp[c] = w2b + (size_t)e * DM * DFF + (size_t)(n0 + r) * DFF + gchunk * 8;
    }

    f32x4 zero = {0.f, 0.f, 0.f, 0.f};
    f32x4 acc[4][4];
#pragma unroll
    for (int i = 0; i < 4; i++)
#pragma unroll
        for (int j = 0; j < 4; j++) acc[i][j] = zero;

    const int mw = w & 1, nw = w >> 1;
    const int fr = l & 15, fk = l >> 4;

    for (int kt = 0; kt < 32; kt++) {
        const int ko = kt * 64;
#pragma unroll
        for (int c = 0; c < 4; c++)
            __builtin_amdgcn_global_load_lds(GP(ap[c] + ko), LP(sm + c * 2048 + w * 512), 16, 0, 0);
#pragma unroll
        for (int c = 0; c < 4; c++)
            __builtin_amdgcn_global_load_lds(GP(bp[c] + ko), LP(sm + 8192 + c * 2048 + w * 512), 16, 0, 0);
        asm volatile("s_waitcnt vmcnt(0)" ::: "memory");
        __syncthreads();
#pragma unroll
        for (int kk = 0; kk < 2; kk++) {
            const int g = kk * 4 + fk;
            bf16x8 af[4], bfr[4];
#pragma unroll
            for (int i = 0; i < 4; i++) {
                int row = mw * 64 + i * 16 + fr;
                af[i] = *(const bf16x8*)&sm[row * 64 + ((g ^ (row & 7)) << 3)];
            }
#pragma unroll
            for (int j = 0; j < 4; j++) {
                int row = nw * 64 + j * 16 + fr;
                bfr[j] = *(const bf16x8*)&sm[8192 + row * 64 + ((g ^ (row & 7)) << 3)];
            }
#pragma unroll
            for (int i = 0; i < 4; i++)
#pragma unroll
                for (int j = 0; j < 4; j++)
                    acc[i][j] = __builtin_amdgcn_mfma_f32_16x16x32_bf16(af[i], bfr[j], acc[i][j], 0, 0, 0);
        }
        __syncthreads();
    }

    const float s2 = w2_scale[e];
#pragma unroll
    for (int i = 0; i < 4; i++)
#pragma unroll
        for (int r = 0; r < 4; r++) {
            int lm = mw * 64 + i * 16 + fk * 4 + r;
            if (m0 + lm < c_n) {
                int tok = btok[b * T_TOK + m0 + lm];
#pragma unroll
                for (int j = 0; j < 4; j++) {
                    int col = n0 + nw * 64 + j * 16 + fr;
                    atomicAdd(out + (size_t)tok * DM + col, acc[i][j][r] * s2);
                }
            }
        }
}

extern "C" void kernel_launch(void* const* d_in, const int* in_sizes, int n_in,
                              void* d_out, int out_size, void* d_ws, size_t ws_size,
                              hipStream_t stream) {
    const float* x      = (const float*)d_in[0];
    const float* gating = (const float*)d_in[1];
    const float* w13q   = (const float*)d_in[2];
    const float* w13s   = (const float*)d_in[3];
    const float* w2q    = (const float*)d_in[4];
    const float* w2s    = (const float*)d_in[5];
    float* out = (float*)d_out;
    char* ws = (char*)d_ws;

    hipMemsetAsync(ws, 0, 4096, stream);
    k_front<<<1056, 256, 0, stream>>>(gating, (int*)(ws + OFF_CNT),
                                      (int*)(ws + OFF_BTOK), (float*)(ws + OFF_BW),
                                      (const float4*)x, (float4*)out,
                                      (unsigned*)(ws + OFF_AMAX));
    k_quant<<<1024, 256, 0, stream>>>((const float4*)x, (unsigned char*)(ws + OFF_XQ),
                                      (const unsigned*)(ws + OFF_AMAX),
                                      (const int*)(ws + OFF_CNT), (int*)(ws + OFF_PBASE),
                                      (int*)(ws + OFF_TMETA), (int*)(ws + OFF_TSE),
                                      (int*)(ws + OFF_TM0));
    k_convw<<<3072, 256, 0, stream>>>((const float4*)w13q, (unsigned char*)(ws + OFF_W13F),
                                      (const float4*)w2q, (short*)(ws + OFF_W2B));
    k_gemm1<<<dim3(32, 144), 256, 0, stream>>>((const unsigned char*)(ws + OFF_XQ),
                                               (const unsigned char*)(ws + OFF_W13F),
                                               (short*)(ws + OFF_H), ws, w13s);
    k_gemm2<<<dim3(16, 144), 256, 0, stream>>>((const short*)(ws + OFF_H), (const short*)(ws + OFF_W2B),
                                               out, ws, w2s);
}